// Round 8
// baseline (198.519 us; speedup 1.0000x reference)
//
#include <hip/hip_runtime.h>
#include <math.h>

#define SEQ   3072
#define DM    1024
#define NH    16
#define DH    64
#define WIN   128
#define DIL   4
#define TSUB  768      // SEQ / DIL

typedef __attribute__((ext_vector_type(8))) short    short8;   // 8 bf16
typedef __attribute__((ext_vector_type(8))) _Float16 half8;    // 8 fp16
typedef __attribute__((ext_vector_type(4))) float    floatx4;  // MFMA C/D

__device__ __forceinline__ float bf2f(unsigned short u) {
    return __uint_as_float(((unsigned)u) << 16);
}
__device__ __forceinline__ unsigned short f2bf(float f) {   // RNE, finite inputs
    unsigned u = __float_as_uint(f);
    return (unsigned short)((u + 0x7FFFu + ((u >> 16) & 1u)) >> 16);
}
__device__ __forceinline__ unsigned short f2h(float f) {
    _Float16 h = (_Float16)f;
    return __builtin_bit_cast(unsigned short, h);
}

// pack 16 fp32 (4 float4) -> 2 short8 bf16, RNE (bit-identical to the old
// convert_kernel, so absmax is unchanged).
__device__ __forceinline__ void cvt16(const float4& f0, const float4& f1,
                                      const float4& f2, const float4& f3,
                                      short8& r0, short8& r1)
{
    r0[0] = (short)f2bf(f0.x); r0[1] = (short)f2bf(f0.y);
    r0[2] = (short)f2bf(f0.z); r0[3] = (short)f2bf(f0.w);
    r0[4] = (short)f2bf(f1.x); r0[5] = (short)f2bf(f1.y);
    r0[6] = (short)f2bf(f1.z); r0[7] = (short)f2bf(f1.w);
    r1[0] = (short)f2bf(f2.x); r1[1] = (short)f2bf(f2.y);
    r1[2] = (short)f2bf(f2.z); r1[3] = (short)f2bf(f2.w);
    r1[4] = (short)f2bf(f3.x); r1[5] = (short)f2bf(f3.y);
    r1[6] = (short)f2bf(f3.z); r1[7] = (short)f2bf(f3.w);
}

// async global->LDS, 16B/lane (used only by attn's K staging).
__device__ __forceinline__ void gload_lds16(const void* g, void* l) {
    __builtin_amdgcn_global_load_lds(
        (const __attribute__((address_space(1))) void*)g,
        (__attribute__((address_space(3))) void*)l, 16, 0, 0);
}

// ---------------------------------------------------------------------------
// QKV GEMM, 128x128 tile, BK=32, reg-staged pipeline (R7 structure, 0 bank
// conflicts verified). NEW: A = fp32 x, W = fp32 weights, converted to bf16
// in registers inside the ds_write slot (post-compute barrier), eliminating
// the convert_kernel pass entirely. fp32 prefetch regs stay live across the
// MFMA section so no vmcnt wait lands before compute.
// LDS swizzle: chunk c of row r at c ^ ((r>>1)&3)  [R7: 0 conflicts].
// ---------------------------------------------------------------------------
template<bool QSCALE>
__device__ __forceinline__ void gemm_qkv_body(const float* __restrict__ A,
                                              const float* __restrict__ W,
                                              const float* __restrict__ bias,
                                              const float* __restrict__ beta,
                                              ushort* __restrict__ C,
                                              int bx, int by)
{
    __shared__ ushort As[128][32];   // 8 KB
    __shared__ ushort Bs[128][32];   // 8 KB

    const int tid  = threadIdx.x;
    const int lane = tid & 63, w = tid >> 6;
    const int ln15 = lane & 15, quad = lane >> 4;
    const int wm = w >> 1, wn = w & 1;

    // staging: thread t -> row t>>1, fp32 half h = t&1 (16 floats)
    const int srow = tid >> 1;
    const int sh   = tid & 1;
    const int sf   = (srow >> 1) & 3;                 // swizzle key
    const float* aG = A + (size_t)(by * 128 + srow) * DM + sh * 16;
    const float* bG = W + (size_t)(bx * 128 + srow) * DM + sh * 16;
    ushort* aL0 = &As[srow][((2 * sh)     ^ sf) * 8];
    ushort* aL1 = &As[srow][((2 * sh + 1) ^ sf) * 8];
    ushort* bL0 = &Bs[srow][((2 * sh)     ^ sf) * 8];
    ushort* bL1 = &Bs[srow][((2 * sh + 1) ^ sf) * 8];

    const floatx4 zero = {0.f, 0.f, 0.f, 0.f};
    floatx4 acc[4][4];
#pragma unroll
    for (int i = 0; i < 4; ++i)
#pragma unroll
        for (int j = 0; j < 4; ++j) acc[i][j] = zero;

    // prologue: tile 0
    float4 fa0 = *(const float4*)aG,        fa1 = *(const float4*)(aG + 4);
    float4 fa2 = *(const float4*)(aG + 8),  fa3 = *(const float4*)(aG + 12);
    float4 fb0 = *(const float4*)bG,        fb1 = *(const float4*)(bG + 4);
    float4 fb2 = *(const float4*)(bG + 8),  fb3 = *(const float4*)(bG + 12);
    {
        short8 ra0, ra1, rb0, rb1;
        cvt16(fa0, fa1, fa2, fa3, ra0, ra1);
        cvt16(fb0, fb1, fb2, fb3, rb0, rb1);
        *(short8*)aL0 = ra0; *(short8*)aL1 = ra1;
        *(short8*)bL0 = rb0; *(short8*)bL1 = rb1;
    }
    __syncthreads();

    const int rf = (ln15 >> 1) & 3;       // frag-read swizzle key
#pragma unroll 2
    for (int k = 0; k < 32; ++k) {
        if (k < 31) {                     // fp32 loads for tile k+1
            const float* aN = aG + (k + 1) * 32;
            const float* bN = bG + (k + 1) * 32;
            fa0 = *(const float4*)aN;       fa1 = *(const float4*)(aN + 4);
            fa2 = *(const float4*)(aN + 8); fa3 = *(const float4*)(aN + 12);
            fb0 = *(const float4*)bN;       fb1 = *(const float4*)(bN + 4);
            fb2 = *(const float4*)(bN + 8); fb3 = *(const float4*)(bN + 12);
        }
        short8 af[4], bf[4];
#pragma unroll
        for (int i = 0; i < 4; ++i)
            af[i] = *(const short8*)&As[wm * 64 + i * 16 + ln15][(quad ^ rf) * 8];
#pragma unroll
        for (int j = 0; j < 4; ++j)
            bf[j] = *(const short8*)&Bs[wn * 64 + j * 16 + ln15][(quad ^ rf) * 8];
#pragma unroll
        for (int i = 0; i < 4; ++i)
#pragma unroll
            for (int j = 0; j < 4; ++j)
                acc[i][j] = __builtin_amdgcn_mfma_f32_16x16x32_bf16(af[i], bf[j], acc[i][j], 0, 0, 0);

        __syncthreads();                  // tile-k LDS reads complete
        if (k < 31) {                     // cvt + ds_write; vmcnt wait lands here
            short8 ra0, ra1, rb0, rb1;
            cvt16(fa0, fa1, fa2, fa3, ra0, ra1);
            cvt16(fb0, fb1, fb2, fb3, rb0, rb1);
            *(short8*)aL0 = ra0; *(short8*)aL1 = ra1;
            *(short8*)bL0 = rb0; *(short8*)bL1 = rb1;
        }
        __syncthreads();                  // tile k+1 resident
    }

#pragma unroll
    for (int j = 0; j < 4; ++j) {
        const int col = bx * 128 + wn * 64 + j * 16 + ln15;
        const float b = bias[col];
        const float scale = QSCALE ? 0.125f * __expf(-beta[col >> 6]) : 1.0f;
#pragma unroll
        for (int i = 0; i < 4; ++i) {
            const int row0 = by * 128 + wm * 64 + i * 16 + quad * 4;
#pragma unroll
            for (int rg = 0; rg < 4; ++rg) {
                float vv = (acc[i][j][rg] + b) * scale;
                C[(size_t)(row0 + rg) * DM + col] = f2bf(vv);
            }
        }
    }
}

// grid (8, 24, 3): z selects Q/K/V. 576 blocks.
__global__ __launch_bounds__(256) void qkv_kernel(
    const float* __restrict__ x,
    const float* __restrict__ Wq, const float* __restrict__ bq,
    const float* __restrict__ Wk, const float* __restrict__ bk,
    const float* __restrict__ Wv, const float* __restrict__ bv,
    const float* __restrict__ beta,
    ushort* __restrict__ q, ushort* __restrict__ k, ushort* __restrict__ v)
{
    const int z = blockIdx.z;
    const float* W = (z == 0) ? Wq : (z == 1) ? Wk : Wv;
    const float* b = (z == 0) ? bq : (z == 1) ? bk : bv;
    ushort*      C = (z == 0) ? q  : (z == 1) ? k  : v;
    if (z == 0)
        gemm_qkv_body<true >(x, W, b, beta, C, blockIdx.x, blockIdx.y);
    else
        gemm_qkv_body<false>(x, W, b, nullptr, C, blockIdx.x, blockIdx.y);
}

// ---------------------------------------------------------------------------
// Output GEMM, 64x64 tile (grid 768 = 3 blocks/CU: the 192-block 128-tile
// version was 0.75 blocks/CU -- one partial round, TLP-starved).
// A = ctx (bf16), B = Wo (fp32, in-reg cvt). Same reg-staged pipeline and
// verified-conflict-free swizzle (read pattern identical to R7's).
// 4 waves as 2x2, wave tile 32x32, 2x2 MFMAs of 16x16x32.
// ---------------------------------------------------------------------------
__global__ __launch_bounds__(256) void out_kernel(
    const ushort* __restrict__ ctxb, const float* __restrict__ Wo,
    const float* __restrict__ bo, float* __restrict__ out)
{
    __shared__ ushort As[64][32];    // 4 KB
    __shared__ ushort Bs[64][32];    // 4 KB

    const int tid  = threadIdx.x;
    const int lane = tid & 63, w = tid >> 6;
    const int ln15 = lane & 15, quad = lane >> 4;
    const int wm = w >> 1, wn = w & 1;
    const int bx = blockIdx.x, by = blockIdx.y;

    // staging: thread t -> row t>>2 (0..63), chunk t&3 (8 elems)
    const int srow = tid >> 2;
    const int sch  = tid & 3;
    const int sf   = (srow >> 1) & 3;
    const ushort* aG = ctxb + (size_t)(by * 64 + srow) * DM + sch * 8;
    const float*  bG = Wo   + (size_t)(bx * 64 + srow) * DM + sch * 8;
    ushort* aL = &As[srow][(sch ^ sf) * 8];
    ushort* bL = &Bs[srow][(sch ^ sf) * 8];

    const floatx4 zero = {0.f, 0.f, 0.f, 0.f};
    floatx4 acc[2][2];
#pragma unroll
    for (int i = 0; i < 2; ++i)
#pragma unroll
        for (int j = 0; j < 2; ++j) acc[i][j] = zero;

    // prologue
    short8 ra = *(const short8*)aG;
    float4 fb0 = *(const float4*)bG, fb1 = *(const float4*)(bG + 4);
    {
        short8 rb;
        rb[0] = (short)f2bf(fb0.x); rb[1] = (short)f2bf(fb0.y);
        rb[2] = (short)f2bf(fb0.z); rb[3] = (short)f2bf(fb0.w);
        rb[4] = (short)f2bf(fb1.x); rb[5] = (short)f2bf(fb1.y);
        rb[6] = (short)f2bf(fb1.z); rb[7] = (short)f2bf(fb1.w);
        *(short8*)aL = ra; *(short8*)bL = rb;
    }
    __syncthreads();

    const int rf = (ln15 >> 1) & 3;
#pragma unroll 2
    for (int k = 0; k < 32; ++k) {
        if (k < 31) {
            ra  = *(const short8*)(aG + (k + 1) * 32);
            fb0 = *(const float4*)(bG + (k + 1) * 32);
            fb1 = *(const float4*)(bG + (k + 1) * 32 + 4);
        }
        short8 af[2], bf[2];
#pragma unroll
        for (int i = 0; i < 2; ++i)
            af[i] = *(const short8*)&As[wm * 32 + i * 16 + ln15][(quad ^ rf) * 8];
#pragma unroll
        for (int j = 0; j < 2; ++j)
            bf[j] = *(const short8*)&Bs[wn * 32 + j * 16 + ln15][(quad ^ rf) * 8];
#pragma unroll
        for (int i = 0; i < 2; ++i)
#pragma unroll
            for (int j = 0; j < 2; ++j)
                acc[i][j] = __builtin_amdgcn_mfma_f32_16x16x32_bf16(af[i], bf[j], acc[i][j], 0, 0, 0);

        __syncthreads();
        if (k < 31) {
            short8 rb;
            rb[0] = (short)f2bf(fb0.x); rb[1] = (short)f2bf(fb0.y);
            rb[2] = (short)f2bf(fb0.z); rb[3] = (short)f2bf(fb0.w);
            rb[4] = (short)f2bf(fb1.x); rb[5] = (short)f2bf(fb1.y);
            rb[6] = (short)f2bf(fb1.z); rb[7] = (short)f2bf(fb1.w);
            *(short8*)aL = ra; *(short8*)bL = rb;
        }
        __syncthreads();
    }

#pragma unroll
    for (int j = 0; j < 2; ++j) {
        const int col = bx * 64 + wn * 32 + j * 16 + ln15;
        const float b = bo[col];
#pragma unroll
        for (int i = 0; i < 2; ++i) {
            const int row0 = by * 64 + wm * 32 + i * 16 + quad * 4;
#pragma unroll
            for (int rg = 0; rg < 4; ++rg)
                out[(size_t)(row0 + rg) * DM + col] = acc[i][j][rg] + b;
        }
    }
}

// ---------------------------------------------------------------------------
// MFMA attention (unchanged from R7).
// ---------------------------------------------------------------------------
struct AttnSmem {
    union {
        ushort Ks[192 * 64];        // [key][dg] ; dg holds dims 8*(dg^(key&7))
        ushort Vt[6 * 4 * 64 * 8];  // [kc][dt][lane][8] fp16, lane-linear
    } u;
    float S[32][195];
    float Rsum[32];
};

__global__ __launch_bounds__(256) void attn_kernel(
    const ushort* __restrict__ q, const ushort* __restrict__ k,
    const ushort* __restrict__ v, ushort* __restrict__ ctx)
{
    __shared__ AttnSmem sm;

    const int tid  = threadIdx.x;
    const int lane = tid & 63, w = tid >> 6;
    const int ln15 = lane & 15, quad = lane >> 4;
    const int t0   = blockIdx.x * 32;
    const int r    = blockIdx.y;
    const int h    = blockIdx.z;
    const int hoff = h * DH;

    // ---- stage K (192 keys x 64 dims) via glds, 6 ops/wave -----------------
    {
        const int kr = lane >> 3;                   // key-in-op 0..7
        const int swz = ((lane & 7) ^ kr) * 8;      // XOR swizzle on global dim
#pragma unroll
        for (int ci = w * 6; ci < w * 6 + 6; ++ci) {
            int key = ci * 8 + kr;
            long grow = 4L * (t0 - 160 + key) + r;  // may be negative -> q buffer
            gload_lds16(k + grow * DM + hoff + swz, &sm.u.Ks[ci * 512]);
        }
    }

    // ---- Q A-frags direct from global (wave w owns qtile w>>1) -------------
    const int qt = w >> 1;
    short8 qf0, qf1;
    {
        int qrow = qt * 16 + ln15;
        const ushort* gq = q + (4L * (t0 + qrow) + r) * DM + hoff + quad * 8;
        qf0 = *(const short8*)gq;
        qf1 = *(const short8*)(gq + 32);
    }

    // ---- V loads into registers (writes to LDS deferred past barrier 2) ----
    short8 vreg[6];
#pragma unroll
    for (int it = 0; it < 6; ++it) {
        int idx = it * 256 + tid;                   // 0..1535
        int key = idx >> 3, d0 = (idx & 7) * 8;
        long grow = 4L * (t0 - 160 + key) + r;
        vreg[it] = *(const short8*)(v + grow * DM + hoff + d0);
    }

    __syncthreads();   // barrier 1: Ks staged (vmcnt drained by sync)

    // ---- QK^T: wave w -> qtile w>>1, ktiles (w&1)*6 .. +5 ------------------
    {
        const floatx4 zero = {0.f, 0.f, 0.f, 0.f};
        const int kt0 = (w & 1) * 6;
        const int lb  = ln15 & 7;
#pragma unroll
        for (int kk2 = 0; kk2 < 6; ++kk2) {
            const int kt  = kt0 + kk2;
            const int key = kt * 16 + ln15;
            short8 b0 = *(const short8*)&sm.u.Ks[key * 64 + ((quad ^ lb) << 3)];
            short8 b1 = *(const short8*)&sm.u.Ks[key * 64 + (((4 + quad) ^ lb) << 3)];
            floatx4 acc = zero;
            acc = __builtin_amdgcn_mfma_f32_16x16x32_bf16(qf0, b0, acc, 0, 0, 0);
            acc = __builtin_amdgcn_mfma_f32_16x16x32_bf16(qf1, b1, acc, 0, 0, 0);
            const int tp = t0 - 160 + key;          // key slot time
#pragma unroll
            for (int rg = 0; rg < 4; ++rg) {
                int qrow = qt * 16 + quad * 4 + rg;
                int tq = t0 + qrow;
                bool ok = (tp >= 0) && (tp <= tq) && (tp > tq - WIN);
                sm.S[qrow][key] = ok ? acc[rg] : -1e30f;
            }
        }
    }

    __syncthreads();   // barrier 2: S complete, Ks reads done (Vt may alias)

    // ---- V transpose -> frag-linear fp16 LDS -------------------------------
#pragma unroll
    for (int it = 0; it < 6; ++it) {
        int idx = it * 256 + tid;
        int key = idx >> 3, d0 = (idx & 7) * 8;
        int kc = key >> 5, qd = (key >> 3) & 3, jj = key & 7;
        short8 sv = vreg[it];
#pragma unroll
        for (int u = 0; u < 8; ++u) {
            int dim = d0 + u, dt = dim >> 4, ln = dim & 15;
            sm.u.Vt[(kc * 4 + dt) * 512 + (qd * 16 + ln) * 8 + jj] =
                f2h(bf2f((unsigned short)sv[u]));
        }
    }

    // ---- softmax: 8 threads/row, stride-8 slot ownership -------------------
    {
        const int sq = tid >> 3, part = tid & 7;
        float m = -1e30f;
#pragma unroll
        for (int j = 0; j < 24; ++j) m = fmaxf(m, sm.S[sq][part + 8 * j]);
#pragma unroll
        for (int o = 1; o < 8; o <<= 1) m = fmaxf(m, __shfl_xor(m, o));
        float sum = 0.f;
#pragma unroll
        for (int j = 0; j < 24; ++j) {
            int ks = part + 8 * j;
            float e = __expf(sm.S[sq][ks] - m);
            sm.S[sq][ks] = e;
            sum += e;
        }
#pragma unroll
        for (int o = 1; o < 8; o <<= 1) sum += __shfl_xor(sum, o);
        if (part == 0) sm.Rsum[sq] = 1.0f / sum;
    }

    __syncthreads();   // barrier 3: Vt + P(S) + Rsum ready

    // ---- PV: wave w -> qtile w&1, dtiles (w>>1)*2 .. +1 --------------------
    {
        const floatx4 zero = {0.f, 0.f, 0.f, 0.f};
        const int qtp = w & 1, dh = w >> 1;
        floatx4 o0 = zero, o1 = zero;
#pragma unroll
        for (int kc = 0; kc < 6; ++kc) {
            const float* ps = &sm.S[qtp * 16 + ln15][kc * 32 + quad * 8];
            half8 pa;
#pragma unroll
            for (int u = 0; u < 8; ++u) pa[u] = (_Float16)ps[u];
            half8 vb0 = *(const half8*)&sm.u.Vt[(kc * 4 + dh * 2 + 0) * 512 + lane * 8];
            half8 vb1 = *(const half8*)&sm.u.Vt[(kc * 4 + dh * 2 + 1) * 512 + lane * 8];
            o0 = __builtin_amdgcn_mfma_f32_16x16x32_f16(pa, vb0, o0, 0, 0, 0);
            o1 = __builtin_amdgcn_mfma_f32_16x16x32_f16(pa, vb1, o1, 0, 0, 0);
        }
#pragma unroll
        for (int rg = 0; rg < 4; ++rg) {
            int qrow = qtp * 16 + quad * 4 + rg;
            float rs = sm.Rsum[qrow];
            long orow = 4L * (t0 + qrow) + r;
            ushort* cp = ctx + orow * DM + hoff + dh * 32 + ln15;
            cp[0]  = f2bf(o0[rg] * rs);
            cp[16] = f2bf(o1[rg] * rs);
        }
    }
}

// ---------------------------------------------------------------------------
// ws layout (all bf16): q, k, v, ctx (SEQ*DM each) = 25 MB.
// convert_kernel is gone: qkv/out read fp32 x/W directly with in-reg cvt.
// ---------------------------------------------------------------------------
extern "C" void kernel_launch(void* const* d_in, const int* in_sizes, int n_in,
                              void* d_out, int out_size, void* d_ws, size_t ws_size,
                              hipStream_t stream)
{
    const float* x    = (const float*)d_in[0];
    const float* beta = (const float*)d_in[1];
    const float* Wq   = (const float*)d_in[2];
    const float* bq   = (const float*)d_in[3];
    const float* Wk   = (const float*)d_in[4];
    const float* bk   = (const float*)d_in[5];
    const float* Wv   = (const float*)d_in[6];
    const float* bv   = (const float*)d_in[7];
    const float* Wo   = (const float*)d_in[8];
    const float* bo   = (const float*)d_in[9];

    ushort* qb   = (ushort*)d_ws;
    ushort* kb   = qb   + (size_t)SEQ * DM;
    ushort* vb   = kb   + (size_t)SEQ * DM;
    ushort* ctxb = vb   + (size_t)SEQ * DM;
    float*  out  = (float*)d_out;

    dim3 gqkv(DM / 128, SEQ / 128, 3);          // (8, 24, 3) = 576 blocks
    qkv_kernel<<<gqkv, 256, 0, stream>>>(x, Wq, bq, Wk, bk, Wv, bv, beta, qb, kb, vb);

    dim3 gattn(TSUB / 32, DIL, NH);             // (24, 4, 16) = 1536 blocks
    attn_kernel<<<gattn, 256, 0, stream>>>(qb, kb, vb, ctxb);

    dim3 gout(DM / 64, SEQ / 64);               // (16, 48) = 768 blocks
    out_kernel<<<gout, 256, 0, stream>>>(ctxb, Wo, bo, out);
}

// Round 9
// 176.490 us; speedup vs baseline: 1.1248x; 1.1248x over previous
//
#include <hip/hip_runtime.h>
#include <math.h>

#define SEQ   3072
#define DM    1024
#define NH    16
#define DH    64
#define WIN   128
#define DIL   4
#define TSUB  768      // SEQ / DIL

typedef __attribute__((ext_vector_type(8))) short    short8;   // 8 bf16
typedef __attribute__((ext_vector_type(8))) _Float16 half8;    // 8 fp16
typedef __attribute__((ext_vector_type(4))) float    floatx4;  // MFMA C/D

__device__ __forceinline__ float bf2f(unsigned short u) {
    return __uint_as_float(((unsigned)u) << 16);
}
__device__ __forceinline__ unsigned short f2bf(float f) {   // RNE, finite inputs
    unsigned u = __float_as_uint(f);
    return (unsigned short)((u + 0x7FFFu + ((u >> 16) & 1u)) >> 16);
}
__device__ __forceinline__ unsigned short f2h(float f) {
    _Float16 h = (_Float16)f;
    return __builtin_bit_cast(unsigned short, h);
}

// async global->LDS, 16B/lane (used only by attn's K staging).
__device__ __forceinline__ void gload_lds16(const void* g, void* l) {
    __builtin_amdgcn_global_load_lds(
        (const __attribute__((address_space(1))) void*)g,
        (__attribute__((address_space(3))) void*)l, 16, 0, 0);
}

// ---------------------------------------------------------------------------
// fp32 -> bf16 conversion (restored: R8 showed fp32 inputs in the latency-
// bound GEMM loop double FETCH and cost 33 us; convert once, read bf16).
// ---------------------------------------------------------------------------
__global__ __launch_bounds__(256) void convert_kernel(
    const float* __restrict__ x,  const float* __restrict__ Wq,
    const float* __restrict__ Wk, const float* __restrict__ Wv,
    const float* __restrict__ Wo,
    ushort* __restrict__ xb,  ushort* __restrict__ Wqb,
    ushort* __restrict__ Wkb, ushort* __restrict__ Wvb,
    ushort* __restrict__ Wob)
{
    const float* s; ushort* d; int n;
    switch (blockIdx.y) {
        case 0: s = x;  d = xb;  n = SEQ * DM; break;
        case 1: s = Wq; d = Wqb; n = DM * DM;  break;
        case 2: s = Wk; d = Wkb; n = DM * DM;  break;
        case 3: s = Wv; d = Wvb; n = DM * DM;  break;
        default: s = Wo; d = Wob; n = DM * DM; break;
    }
    int i = (blockIdx.x * 256 + threadIdx.x) * 4;
    if (i >= n) return;
    float4 v = *(const float4*)&s[i];
    ushort4 o = { f2bf(v.x), f2bf(v.y), f2bf(v.z), f2bf(v.w) };
    *(ushort4*)&d[i] = o;
}

// ---------------------------------------------------------------------------
// QKV GEMM: 128x128 tile, BK=64 (16 iters of 32 MFMAs -- 2x the MFMA per
// barrier vs R7's BK=32, to amortize the ~1200-cyc/iter exposed latency the
// 2-barrier K-loop structurally carries). Reg-staged single LDS buffer
// (2 x 16 KB). 3-bit XOR swizzle pos = chunk ^ ((row>>1)&7): with 128-B rows
// a 2-bit key would confine frag reads to 16 banks; 3-bit spreads every
// access across all 8 chunk slots (8 lanes/bank-quad = schedulable-free,
// the pattern class R7 measured at 0 conflicts).
// ---------------------------------------------------------------------------
template<bool QSCALE>
__device__ __forceinline__ void gemm_qkv_body(const ushort* __restrict__ A,
                                              const ushort* __restrict__ W,
                                              const float* __restrict__ bias,
                                              const float* __restrict__ beta,
                                              ushort* __restrict__ C,
                                              int bx, int by)
{
    __shared__ ushort As[128][64];   // 16 KB
    __shared__ ushort Bs[128][64];   // 16 KB

    const int tid  = threadIdx.x;
    const int lane = tid & 63, w = tid >> 6;
    const int ln15 = lane & 15, quad = lane >> 4;
    const int wm = w >> 1, wn = w & 1;

    // staging: thread t -> row t>>1 (0..127), half sh = t&1 (chunks 4sh..4sh+3)
    const int srow = tid >> 1;
    const int sh   = tid & 1;
    const int sk   = (srow >> 1) & 7;          // 3-bit swizzle key
    const ushort* aG = A + (size_t)(by * 128 + srow) * DM + sh * 32;
    const ushort* bG = W + (size_t)(bx * 128 + srow) * DM + sh * 32;
    ushort* aL[4]; ushort* bL[4];
#pragma unroll
    for (int c = 0; c < 4; ++c) {
        int pos = (4 * sh + c) ^ sk;
        aL[c] = &As[srow][pos * 8];
        bL[c] = &Bs[srow][pos * 8];
    }

    const floatx4 zero = {0.f, 0.f, 0.f, 0.f};
    floatx4 acc[4][4];
#pragma unroll
    for (int i = 0; i < 4; ++i)
#pragma unroll
        for (int j = 0; j < 4; ++j) acc[i][j] = zero;

    // prologue: tile 0
    short8 ra[4], rb[4];
#pragma unroll
    for (int c = 0; c < 4; ++c) {
        ra[c] = *(const short8*)(aG + 8 * c);
        rb[c] = *(const short8*)(bG + 8 * c);
    }
#pragma unroll
    for (int c = 0; c < 4; ++c) { *(short8*)aL[c] = ra[c]; *(short8*)bL[c] = rb[c]; }
    __syncthreads();

    const int rf = (ln15 >> 1) & 7;            // frag-read swizzle key
#pragma unroll 2
    for (int k = 0; k < 16; ++k) {
        if (k < 15) {                          // loads for tile k+1 (regs)
            const ushort* aN = aG + (k + 1) * 64;
            const ushort* bN = bG + (k + 1) * 64;
#pragma unroll
            for (int c = 0; c < 4; ++c) {
                ra[c] = *(const short8*)(aN + 8 * c);
                rb[c] = *(const short8*)(bN + 8 * c);
            }
        }
#pragma unroll
        for (int s = 0; s < 2; ++s) {          // two K=32 substeps
            short8 af[4], bf[4];
#pragma unroll
            for (int i = 0; i < 4; ++i)
                af[i] = *(const short8*)&As[wm * 64 + i * 16 + ln15][((s * 4 + quad) ^ rf) * 8];
#pragma unroll
            for (int j = 0; j < 4; ++j)
                bf[j] = *(const short8*)&Bs[wn * 64 + j * 16 + ln15][((s * 4 + quad) ^ rf) * 8];
#pragma unroll
            for (int i = 0; i < 4; ++i)
#pragma unroll
                for (int j = 0; j < 4; ++j)
                    acc[i][j] = __builtin_amdgcn_mfma_f32_16x16x32_bf16(af[i], bf[j], acc[i][j], 0, 0, 0);
        }
        __syncthreads();                       // tile-k LDS reads complete
        if (k < 15) {                          // vmcnt wait lands here (post-compute)
#pragma unroll
            for (int c = 0; c < 4; ++c) { *(short8*)aL[c] = ra[c]; *(short8*)bL[c] = rb[c]; }
        }
        __syncthreads();                       // tile k+1 resident
    }

#pragma unroll
    for (int j = 0; j < 4; ++j) {
        const int col = bx * 128 + wn * 64 + j * 16 + ln15;
        const float b = bias[col];
        const float scale = QSCALE ? 0.125f * __expf(-beta[col >> 6]) : 1.0f;
#pragma unroll
        for (int i = 0; i < 4; ++i) {
            const int row0 = by * 128 + wm * 64 + i * 16 + quad * 4;
#pragma unroll
            for (int rg = 0; rg < 4; ++rg) {
                float vv = (acc[i][j][rg] + b) * scale;
                C[(size_t)(row0 + rg) * DM + col] = f2bf(vv);
            }
        }
    }
}

// grid (8, 24, 3): z selects Q/K/V. 576 blocks.
__global__ __launch_bounds__(256) void qkv_kernel(
    const ushort* __restrict__ xb,
    const ushort* __restrict__ Wqb, const float* __restrict__ bq,
    const ushort* __restrict__ Wkb, const float* __restrict__ bk,
    const ushort* __restrict__ Wvb, const float* __restrict__ bv,
    const float* __restrict__ beta,
    ushort* __restrict__ q, ushort* __restrict__ k, ushort* __restrict__ v)
{
    const int z = blockIdx.z;
    const ushort* W = (z == 0) ? Wqb : (z == 1) ? Wkb : Wvb;
    const float*  b = (z == 0) ? bq  : (z == 1) ? bk  : bv;
    ushort*       C = (z == 0) ? q   : (z == 1) ? k   : v;
    if (z == 0)
        gemm_qkv_body<true >(xb, W, b, beta, C, blockIdx.x, blockIdx.y);
    else
        gemm_qkv_body<false>(xb, W, b, nullptr, C, blockIdx.x, blockIdx.y);
}

// ---------------------------------------------------------------------------
// Output GEMM: 64x64 tile, BK=64, bf16 inputs, grid 768 (3 blocks/CU).
// Same reg-staged loop + 3-bit swizzle (rows are 128 B here too).
// 4 waves 2x2, wave tile 32x32, 2 substeps x 2x2 MFMAs.
// ---------------------------------------------------------------------------
__global__ __launch_bounds__(256) void out_kernel(
    const ushort* __restrict__ ctxb, const ushort* __restrict__ Wob,
    const float* __restrict__ bo, float* __restrict__ out)
{
    __shared__ ushort As[64][64];    // 8 KB
    __shared__ ushort Bs[64][64];    // 8 KB

    const int tid  = threadIdx.x;
    const int lane = tid & 63, w = tid >> 6;
    const int ln15 = lane & 15, quad = lane >> 4;
    const int wm = w >> 1, wn = w & 1;
    const int bx = blockIdx.x, by = blockIdx.y;

    // staging: thread t -> row t>>2 (0..63), quarter sq = t&3 (chunks 2sq,2sq+1)
    const int srow = tid >> 2;
    const int sq   = tid & 3;
    const int sk   = (srow >> 1) & 7;
    const ushort* aG = ctxb + (size_t)(by * 64 + srow) * DM + sq * 16;
    const ushort* bG = Wob  + (size_t)(bx * 64 + srow) * DM + sq * 16;
    ushort* aL[2]; ushort* bL[2];
#pragma unroll
    for (int c = 0; c < 2; ++c) {
        int pos = (2 * sq + c) ^ sk;
        aL[c] = &As[srow][pos * 8];
        bL[c] = &Bs[srow][pos * 8];
    }

    const floatx4 zero = {0.f, 0.f, 0.f, 0.f};
    floatx4 acc[2][2];
#pragma unroll
    for (int i = 0; i < 2; ++i)
#pragma unroll
        for (int j = 0; j < 2; ++j) acc[i][j] = zero;

    // prologue
    short8 ra[2], rb[2];
#pragma unroll
    for (int c = 0; c < 2; ++c) {
        ra[c] = *(const short8*)(aG + 8 * c);
        rb[c] = *(const short8*)(bG + 8 * c);
    }
#pragma unroll
    for (int c = 0; c < 2; ++c) { *(short8*)aL[c] = ra[c]; *(short8*)bL[c] = rb[c]; }
    __syncthreads();

    const int rf = (ln15 >> 1) & 7;
#pragma unroll 2
    for (int k = 0; k < 16; ++k) {
        if (k < 15) {
            const ushort* aN = aG + (k + 1) * 64;
            const ushort* bN = bG + (k + 1) * 64;
#pragma unroll
            for (int c = 0; c < 2; ++c) {
                ra[c] = *(const short8*)(aN + 8 * c);
                rb[c] = *(const short8*)(bN + 8 * c);
            }
        }
#pragma unroll
        for (int s = 0; s < 2; ++s) {
            short8 af[2], bf[2];
#pragma unroll
            for (int i = 0; i < 2; ++i)
                af[i] = *(const short8*)&As[wm * 32 + i * 16 + ln15][((s * 4 + quad) ^ rf) * 8];
#pragma unroll
            for (int j = 0; j < 2; ++j)
                bf[j] = *(const short8*)&Bs[wn * 32 + j * 16 + ln15][((s * 4 + quad) ^ rf) * 8];
#pragma unroll
            for (int i = 0; i < 2; ++i)
#pragma unroll
                for (int j = 0; j < 2; ++j)
                    acc[i][j] = __builtin_amdgcn_mfma_f32_16x16x32_bf16(af[i], bf[j], acc[i][j], 0, 0, 0);
        }
        __syncthreads();
        if (k < 15) {
#pragma unroll
            for (int c = 0; c < 2; ++c) { *(short8*)aL[c] = ra[c]; *(short8*)bL[c] = rb[c]; }
        }
        __syncthreads();
    }

#pragma unroll
    for (int j = 0; j < 2; ++j) {
        const int col = bx * 64 + wn * 32 + j * 16 + ln15;
        const float b = bo[col];
#pragma unroll
        for (int i = 0; i < 2; ++i) {
            const int row0 = by * 64 + wm * 32 + i * 16 + quad * 4;
#pragma unroll
            for (int rg = 0; rg < 4; ++rg)
                out[(size_t)(row0 + rg) * DM + col] = acc[i][j][rg] + b;
        }
    }
}

// ---------------------------------------------------------------------------
// MFMA attention (unchanged from R7/R8).
// ---------------------------------------------------------------------------
struct AttnSmem {
    union {
        ushort Ks[192 * 64];        // [key][dg] ; dg holds dims 8*(dg^(key&7))
        ushort Vt[6 * 4 * 64 * 8];  // [kc][dt][lane][8] fp16, lane-linear
    } u;
    float S[32][195];
    float Rsum[32];
};

__global__ __launch_bounds__(256) void attn_kernel(
    const ushort* __restrict__ q, const ushort* __restrict__ k,
    const ushort* __restrict__ v, ushort* __restrict__ ctx)
{
    __shared__ AttnSmem sm;

    const int tid  = threadIdx.x;
    const int lane = tid & 63, w = tid >> 6;
    const int ln15 = lane & 15, quad = lane >> 4;
    const int t0   = blockIdx.x * 32;
    const int r    = blockIdx.y;
    const int h    = blockIdx.z;
    const int hoff = h * DH;

    // ---- stage K (192 keys x 64 dims) via glds, 6 ops/wave -----------------
    {
        const int kr = lane >> 3;                   // key-in-op 0..7
        const int swz = ((lane & 7) ^ kr) * 8;      // XOR swizzle on global dim
#pragma unroll
        for (int ci = w * 6; ci < w * 6 + 6; ++ci) {
            int key = ci * 8 + kr;
            long grow = 4L * (t0 - 160 + key) + r;  // may be negative -> q buffer
            gload_lds16(k + grow * DM + hoff + swz, &sm.u.Ks[ci * 512]);
        }
    }

    // ---- Q A-frags direct from global (wave w owns qtile w>>1) -------------
    const int qt = w >> 1;
    short8 qf0, qf1;
    {
        int qrow = qt * 16 + ln15;
        const ushort* gq = q + (4L * (t0 + qrow) + r) * DM + hoff + quad * 8;
        qf0 = *(const short8*)gq;
        qf1 = *(const short8*)(gq + 32);
    }

    // ---- V loads into registers (writes to LDS deferred past barrier 2) ----
    short8 vreg[6];
#pragma unroll
    for (int it = 0; it < 6; ++it) {
        int idx = it * 256 + tid;                   // 0..1535
        int key = idx >> 3, d0 = (idx & 7) * 8;
        long grow = 4L * (t0 - 160 + key) + r;
        vreg[it] = *(const short8*)(v + grow * DM + hoff + d0);
    }

    __syncthreads();   // barrier 1: Ks staged (vmcnt drained by sync)

    // ---- QK^T: wave w -> qtile w>>1, ktiles (w&1)*6 .. +5 ------------------
    {
        const floatx4 zero = {0.f, 0.f, 0.f, 0.f};
        const int kt0 = (w & 1) * 6;
        const int lb  = ln15 & 7;
#pragma unroll
        for (int kk2 = 0; kk2 < 6; ++kk2) {
            const int kt  = kt0 + kk2;
            const int key = kt * 16 + ln15;
            short8 b0 = *(const short8*)&sm.u.Ks[key * 64 + ((quad ^ lb) << 3)];
            short8 b1 = *(const short8*)&sm.u.Ks[key * 64 + (((4 + quad) ^ lb) << 3)];
            floatx4 acc = zero;
            acc = __builtin_amdgcn_mfma_f32_16x16x32_bf16(qf0, b0, acc, 0, 0, 0);
            acc = __builtin_amdgcn_mfma_f32_16x16x32_bf16(qf1, b1, acc, 0, 0, 0);
            const int tp = t0 - 160 + key;          // key slot time
#pragma unroll
            for (int rg = 0; rg < 4; ++rg) {
                int qrow = qt * 16 + quad * 4 + rg;
                int tq = t0 + qrow;
                bool ok = (tp >= 0) && (tp <= tq) && (tp > tq - WIN);
                sm.S[qrow][key] = ok ? acc[rg] : -1e30f;
            }
        }
    }

    __syncthreads();   // barrier 2: S complete, Ks reads done (Vt may alias)

    // ---- V transpose -> frag-linear fp16 LDS -------------------------------
#pragma unroll
    for (int it = 0; it < 6; ++it) {
        int idx = it * 256 + tid;
        int key = idx >> 3, d0 = (idx & 7) * 8;
        int kc = key >> 5, qd = (key >> 3) & 3, jj = key & 7;
        short8 sv = vreg[it];
#pragma unroll
        for (int u = 0; u < 8; ++u) {
            int dim = d0 + u, dt = dim >> 4, ln = dim & 15;
            sm.u.Vt[(kc * 4 + dt) * 512 + (qd * 16 + ln) * 8 + jj] =
                f2h(bf2f((unsigned short)sv[u]));
        }
    }

    // ---- softmax: 8 threads/row, stride-8 slot ownership -------------------
    {
        const int sq = tid >> 3, part = tid & 7;
        float m = -1e30f;
#pragma unroll
        for (int j = 0; j < 24; ++j) m = fmaxf(m, sm.S[sq][part + 8 * j]);
#pragma unroll
        for (int o = 1; o < 8; o <<= 1) m = fmaxf(m, __shfl_xor(m, o));
        float sum = 0.f;
#pragma unroll
        for (int j = 0; j < 24; ++j) {
            int ks = part + 8 * j;
            float e = __expf(sm.S[sq][ks] - m);
            sm.S[sq][ks] = e;
            sum += e;
        }
#pragma unroll
        for (int o = 1; o < 8; o <<= 1) sum += __shfl_xor(sum, o);
        if (part == 0) sm.Rsum[sq] = 1.0f / sum;
    }

    __syncthreads();   // barrier 3: Vt + P(S) + Rsum ready

    // ---- PV: wave w -> qtile w&1, dtiles (w>>1)*2 .. +1 --------------------
    {
        const floatx4 zero = {0.f, 0.f, 0.f, 0.f};
        const int qtp = w & 1, dh = w >> 1;
        floatx4 o0 = zero, o1 = zero;
#pragma unroll
        for (int kc = 0; kc < 6; ++kc) {
            const float* ps = &sm.S[qtp * 16 + ln15][kc * 32 + quad * 8];
            half8 pa;
#pragma unroll
            for (int u = 0; u < 8; ++u) pa[u] = (_Float16)ps[u];
            half8 vb0 = *(const half8*)&sm.u.Vt[(kc * 4 + dh * 2 + 0) * 512 + lane * 8];
            half8 vb1 = *(const half8*)&sm.u.Vt[(kc * 4 + dh * 2 + 1) * 512 + lane * 8];
            o0 = __builtin_amdgcn_mfma_f32_16x16x32_f16(pa, vb0, o0, 0, 0, 0);
            o1 = __builtin_amdgcn_mfma_f32_16x16x32_f16(pa, vb1, o1, 0, 0, 0);
        }
#pragma unroll
        for (int rg = 0; rg < 4; ++rg) {
            int qrow = qtp * 16 + quad * 4 + rg;
            float rs = sm.Rsum[qrow];
            long orow = 4L * (t0 + qrow) + r;
            ushort* cp = ctx + orow * DM + hoff + dh * 32 + ln15;
            cp[0]  = f2bf(o0[rg] * rs);
            cp[16] = f2bf(o1[rg] * rs);
        }
    }
}

// ---------------------------------------------------------------------------
// ws layout (all bf16): q, k, v, ctx (SEQ*DM each), x, Wq, Wk, Wv, Wo.
// ---------------------------------------------------------------------------
extern "C" void kernel_launch(void* const* d_in, const int* in_sizes, int n_in,
                              void* d_out, int out_size, void* d_ws, size_t ws_size,
                              hipStream_t stream)
{
    const float* x    = (const float*)d_in[0];
    const float* beta = (const float*)d_in[1];
    const float* Wq   = (const float*)d_in[2];
    const float* bq   = (const float*)d_in[3];
    const float* Wk   = (const float*)d_in[4];
    const float* bk   = (const float*)d_in[5];
    const float* Wv   = (const float*)d_in[6];
    const float* bv   = (const float*)d_in[7];
    const float* Wo   = (const float*)d_in[8];
    const float* bo   = (const float*)d_in[9];

    ushort* qb   = (ushort*)d_ws;
    ushort* kb   = qb   + (size_t)SEQ * DM;
    ushort* vb   = kb   + (size_t)SEQ * DM;
    ushort* ctxb = vb   + (size_t)SEQ * DM;
    ushort* xb   = ctxb + (size_t)SEQ * DM;
    ushort* Wqb  = xb   + (size_t)SEQ * DM;
    ushort* Wkb  = Wqb  + (size_t)DM * DM;
    ushort* Wvb  = Wkb  + (size_t)DM * DM;
    ushort* Wob  = Wvb  + (size_t)DM * DM;
    float*  out  = (float*)d_out;

    dim3 gcv(SEQ * DM / 4 / 256, 5);
    convert_kernel<<<gcv, 256, 0, stream>>>(x, Wq, Wk, Wv, Wo, xb, Wqb, Wkb, Wvb, Wob);

    dim3 gqkv(DM / 128, SEQ / 128, 3);          // (8, 24, 3) = 576 blocks
    qkv_kernel<<<gqkv, 256, 0, stream>>>(xb, Wqb, bq, Wkb, bk, Wvb, bv, beta, qb, kb, vb);

    dim3 gattn(TSUB / 32, DIL, NH);             // (24, 4, 16) = 1536 blocks
    attn_kernel<<<gattn, 256, 0, stream>>>(qb, kb, vb, ctxb);

    dim3 gout(DM / 64, SEQ / 64);               // (16, 48) = 768 blocks
    out_kernel<<<gout, 256, 0, stream>>>(ctxb, Wob, bo, out);
}